// Round 8
// baseline (228.296 us; speedup 1.0000x reference)
//
#include <hip/hip_runtime.h>
#include <math.h>

// Problem constants (fixed by reference)
#define B_ 8
#define N_ 384
#define D_ 256
#define H_ 1024
#define GRID 192

typedef __bf16 bh;
typedef __bf16 bh4    __attribute__((ext_vector_type(4)));
typedef __bf16 bf16x8 __attribute__((ext_vector_type(8)));
typedef float  f32x4  __attribute__((ext_vector_type(4)));
typedef _Float16 h2   __attribute__((ext_vector_type(2)));

#if __has_builtin(__builtin_amdgcn_fdot2)
#define FDOT2(a,b,c) __builtin_amdgcn_fdot2((a),(b),(c),false)
#else
#define FDOT2(a,b,c) ((c) + (float)(a).x*(float)(b).x + (float)(a).y*(float)(b).y)
#endif

// async global->LDS, 16B per lane; HW dest = wave-uniform base + lane*16B.
#define GLDS16(gp, lp) __builtin_amdgcn_global_load_lds( \
    (const __attribute__((address_space(1))) unsigned*)(gp), \
    (__attribute__((address_space(3))) unsigned*)(lp), 16, 0, 0)

__device__ inline h2 habs2(h2 x) {
    unsigned u = __builtin_bit_cast(unsigned, x) & 0x7fff7fffu;
    return __builtin_bit_cast(h2, u);
}
__device__ inline void split2(float v, bh& h, bh& l) {
    h = (bh)v; l = (bh)(v - (float)h);
}
// box_num logically int64; harness may hand int32. box_num >= 1 always, so
// int64-LE layout has all odd words zero -> runtime-detectable.
__device__ inline int load_boxnum(const int* __restrict__ p, int b) {
    bool is64 = ((p[1] | p[3] | p[5] | p[7]) == 0);
    return is64 ? p[2 * b] : p[b];
}

// grid barrier: monotonic target; release via syncthreads + agent fence,
// acquire via atomic load + fence (writer XCD L2 writeback / reader inv).
__device__ inline void gbar(unsigned* c, unsigned target) {
    __syncthreads();
    if (threadIdx.x == 0) {
        __threadfence();
        __hip_atomic_fetch_add(c, 1u, __ATOMIC_ACQ_REL, __HIP_MEMORY_SCOPE_AGENT);
        while (__hip_atomic_load(c, __ATOMIC_ACQUIRE, __HIP_MEMORY_SCOPE_AGENT) < target)
            __builtin_amdgcn_s_sleep(2);
        __threadfence();
    }
    __syncthreads();
}

__global__ __launch_bounds__(256) void fused_kernel(
        const float* __restrict__ x, const float* __restrict__ adj,
        const int* __restrict__ box_num,
        const float* __restrict__ fc1_w, const float* __restrict__ fc1_b,
        const float* __restrict__ fc2_w, const float* __restrict__ fc2_b,
        const float* __restrict__ learn_w,
        float* __restrict__ soft_adj, float* __restrict__ xhat,
        bh* __restrict__ wsb, unsigned* __restrict__ cnt) {
    __shared__ __align__(16) unsigned char smem[32768];
    const int tid = threadIdx.x, lane = tid & 63, w = tid >> 6;
    const int bidx = blockIdx.x;
    const int gtid = bidx * 256 + tid;

    // ws plane layout (bh units)
    bh* xh  = wsb;
    bh* xl  = xh  + 786432;
    bh* w1h = xl  + 786432;
    bh* w1l = w1h + 262144;
    bh* w2h = w1l + 262144;
    bh* w2l = w2h + 262144;
    bh* c1h = w2l + 262144;
    bh* c1l = c1h + 3145728;

    // ---------------- phase 0: split x, fc1_w, fc2_w into hi/lo planes ----------------
    {
        #pragma unroll
        for (int it = 0; it < 4; it++) {          // x: 196608 float4, exact
            int idx = it * (GRID * 256) + gtid;
            float4 v = ((const float4*)x)[idx];
            float f[4] = {v.x, v.y, v.z, v.w};
            bh4 hv, lv;
            #pragma unroll
            for (int i = 0; i < 4; i++) { bh h, l; split2(f[i], h, l); hv[i] = h; lv[i] = l; }
            *(bh4*)&xh[4 * (size_t)idx] = hv;
            *(bh4*)&xl[4 * (size_t)idx] = lv;
        }
        #pragma unroll
        for (int it = 0; it < 2; it++) {          // w1: 65536 f4 (guarded)
            int idx = it * (GRID * 256) + gtid;
            if (idx < 65536) {
                float4 v = ((const float4*)fc1_w)[idx];
                float f[4] = {v.x, v.y, v.z, v.w};
                bh4 hv, lv;
                #pragma unroll
                for (int i = 0; i < 4; i++) { bh h, l; split2(f[i], h, l); hv[i] = h; lv[i] = l; }
                *(bh4*)&w1h[4 * (size_t)idx] = hv;
                *(bh4*)&w1l[4 * (size_t)idx] = lv;
            }
        }
        #pragma unroll
        for (int it = 0; it < 2; it++) {          // w2: 65536 f4 (guarded)
            int idx = it * (GRID * 256) + gtid;
            if (idx < 65536) {
                float4 v = ((const float4*)fc2_w)[idx];
                float f[4] = {v.x, v.y, v.z, v.w};
                bh4 hv, lv;
                #pragma unroll
                for (int i = 0; i < 4; i++) { bh h, l; split2(f[i], h, l); hv[i] = h; lv[i] = l; }
                *(bh4*)&w2h[4 * (size_t)idx] = hv;
                *(bh4*)&w2l[4 * (size_t)idx] = lv;
            }
        }
    }
    gbar(cnt, GRID);

    // ---------------- phase 1: c1 = relu(x @ W1^T + b1), split hi/lo out ----------------
    // 128x128 tile, BK=32; 8 n-tiles x 24 m-tiles = 192 = grid. 4 waves (2x2 of 64x64).
    {
        bh* lds = (bh*)smem;
        const int mt = bidx >> 3, nt = bidx & 7;
        const int m0 = mt * 128, n0 = nt * 128;
        const int lr = lane >> 2, kb = lane & 3;
        const int kbp = kb ^ ((lr >> 1) & 3);
        const bh* psrc; int rowbase;
        if (w == 0)      { psrc = xh;  rowbase = m0; }
        else if (w == 1) { psrc = xl;  rowbase = m0; }
        else if (w == 2) { psrc = w1h; rowbase = n0; }
        else             { psrc = w1l; rowbase = n0; }
        const bh* gsrc = psrc + (size_t)(rowbase + lr) * 256 + kbp * 8;
        bh* lwb = &lds[w * 4096 + lane * 8];
        const int l15 = lane & 15, q = lane >> 4;
        const int swq = q ^ ((l15 >> 1) & 3);
        const int wm = (w & 1) * 64, wn = (w >> 1) * 64;

        f32x4 acc[4][4] = {};
        for (int k0 = 0; k0 < 256; k0 += 32) {
            __syncthreads();
            #pragma unroll
            for (int s = 0; s < 8; s++)
                GLDS16(gsrc + (size_t)s * 4096 + k0, lwb + s * 512);
            __syncthreads();
            bf16x8 fa[4][2], fb[4][2];
            #pragma unroll
            for (int i = 0; i < 4; i++) {
                int ra = wm + i * 16 + l15;
                int rb = wn + i * 16 + l15;
                fa[i][0] = *(const bf16x8*)&lds[        ra * 32 + swq * 8];
                fa[i][1] = *(const bf16x8*)&lds[ 4096 + ra * 32 + swq * 8];
                fb[i][0] = *(const bf16x8*)&lds[ 8192 + rb * 32 + swq * 8];
                fb[i][1] = *(const bf16x8*)&lds[12288 + rb * 32 + swq * 8];
            }
            #pragma unroll
            for (int mi = 0; mi < 4; mi++)
                #pragma unroll
                for (int ni = 0; ni < 4; ni++) {
                    acc[mi][ni] = __builtin_amdgcn_mfma_f32_16x16x32_bf16(fa[mi][0], fb[ni][0], acc[mi][ni], 0, 0, 0);
                    acc[mi][ni] = __builtin_amdgcn_mfma_f32_16x16x32_bf16(fa[mi][0], fb[ni][1], acc[mi][ni], 0, 0, 0);
                    acc[mi][ni] = __builtin_amdgcn_mfma_f32_16x16x32_bf16(fa[mi][1], fb[ni][0], acc[mi][ni], 0, 0, 0);
                }
        }
        #pragma unroll
        for (int ni = 0; ni < 4; ni++) {
            int col = n0 + wn + ni * 16 + l15;
            float bb = fc1_b[col];
            #pragma unroll
            for (int mi = 0; mi < 4; mi++)
                #pragma unroll
                for (int reg = 0; reg < 4; reg++) {
                    int row = m0 + wm + mi * 16 + q * 4 + reg;
                    float v = fmaxf(acc[mi][ni][reg] + bb, 0.f);
                    bh h, l; split2(v, h, l);
                    size_t off = (size_t)row * H_ + col;
                    c1h[off] = h; c1l[off] = l;
                }
        }
    }
    gbar(cnt, 2 * GRID);

    // ---------------- phase 2: xhat = c1 @ W2^T + b2 ----------------
    // 64x64 tile, BK=64; 48 m-tiles x 4 n-tiles = 192 = grid. 4 waves (2x2 of 32x32).
    {
        bh* lds = (bh*)smem;
        const int mt = bidx >> 2, nt = bidx & 3;
        const int m0 = mt * 64, n0 = nt * 64;
        const int lr8 = lane >> 3, kb = lane & 7;
        const int kbp = kb ^ lr8;
        const bh* g2;
        if (w == 0)      g2 = c1h + (size_t)(m0 + lr8) * 1024;
        else if (w == 1) g2 = c1l + (size_t)(m0 + lr8) * 1024;
        else if (w == 2) g2 = w2h + (size_t)(n0 + lr8) * 1024;
        else             g2 = w2l + (size_t)(n0 + lr8) * 1024;
        g2 += kbp * 8;
        bh* lwb = &lds[w * 4096 + lane * 8];
        const int l15 = lane & 15, q = lane >> 4;
        const int wm = (w & 1) * 32, wn = (w >> 1) * 32;

        f32x4 acc[2][2] = {};
        for (int k0 = 0; k0 < 1024; k0 += 64) {
            __syncthreads();
            #pragma unroll
            for (int s = 0; s < 8; s++)
                GLDS16(g2 + (size_t)s * 8192 + k0, lwb + s * 512);
            __syncthreads();
            #pragma unroll
            for (int ks = 0; ks < 2; ks++) {
                bf16x8 fa[2][2], fb[2][2];
                #pragma unroll
                for (int mi = 0; mi < 2; mi++) {
                    int r = wm + mi * 16 + l15;
                    int pos = (ks * 4 + q) ^ (l15 & 7);
                    fa[mi][0] = *(const bf16x8*)&lds[       r * 64 + pos * 8];
                    fa[mi][1] = *(const bf16x8*)&lds[4096 + r * 64 + pos * 8];
                }
                #pragma unroll
                for (int ni = 0; ni < 2; ni++) {
                    int r = wn + ni * 16 + l15;
                    int pos = (ks * 4 + q) ^ (l15 & 7);
                    fb[ni][0] = *(const bf16x8*)&lds[ 8192 + r * 64 + pos * 8];
                    fb[ni][1] = *(const bf16x8*)&lds[12288 + r * 64 + pos * 8];
                }
                #pragma unroll
                for (int mi = 0; mi < 2; mi++)
                    #pragma unroll
                    for (int ni = 0; ni < 2; ni++) {
                        acc[mi][ni] = __builtin_amdgcn_mfma_f32_16x16x32_bf16(fa[mi][0], fb[ni][0], acc[mi][ni], 0, 0, 0);
                        acc[mi][ni] = __builtin_amdgcn_mfma_f32_16x16x32_bf16(fa[mi][0], fb[ni][1], acc[mi][ni], 0, 0, 0);
                        acc[mi][ni] = __builtin_amdgcn_mfma_f32_16x16x32_bf16(fa[mi][1], fb[ni][0], acc[mi][ni], 0, 0, 0);
                    }
            }
        }
        #pragma unroll
        for (int ni = 0; ni < 2; ni++) {
            int col = n0 + wn + ni * 16 + l15;
            float bb = fc2_b[col];
            #pragma unroll
            for (int mi = 0; mi < 2; mi++)
                #pragma unroll
                for (int reg = 0; reg < 4; reg++) {
                    int row = m0 + wm + mi * 16 + q * 4 + reg;
                    xhat[(size_t)row * D_ + col] = acc[mi][ni][reg] + bb;
                }
        }
    }
    gbar(cnt, 3 * GRID);

    // ---------------- phase 3: dist (weighted L1 + mask + leaky) + softmax, fused ----------------
    // 192 blocks = 8 batches x 24 row-blocks of 16 rows. j processed in 12 chunks of 32.
    // LDS (h2 = 4 bytes): Xi 16x140 (8960 B) | Xj 32x140 (17920 B) | Ws 128 (512 B) = 27392 B.
    // k loop: 32 iters x uint4 (4 h2 = 8 floats) covers all 128 h2 per row.  [r7 bug: stride 8, 16 iters -> half of k skipped]
    {
        h2* Xi = (h2*)smem;                           // [16][140]
        h2* Xj = (h2*)(smem + 8960);                  // [32][140]
        h2* Ws = (h2*)(smem + 8960 + 17920);          // [128]
        const int b = bidx / 24, rb = bidx % 24;
        const int r0 = rb * 16;
        const int ty = tid >> 4, tx = tid & 15;

        float sumw = learn_w[lane] + learn_w[lane + 64] + learn_w[lane + 128] + learn_w[lane + 192];
        #pragma unroll
        for (int off = 32; off > 0; off >>= 1) sumw += __shfl_xor(sumw, off);

        const float* xb = xhat + (size_t)b * N_ * D_;
        __syncthreads();   // smem still held gemm2 data; ensure all prior reads done
        if (tid < 64) {
            float4 wv = ((const float4*)learn_w)[tid];
            Ws[tid * 2]     = (h2){(_Float16)wv.x, (_Float16)wv.y};
            Ws[tid * 2 + 1] = (h2){(_Float16)wv.z, (_Float16)wv.w};
        }
        {   // stage Xi: 16 rows x 256 cols; thread (row=tid>>4) covers 16 floats at (tid&15)*16
            const int row = tid >> 4, cf = (tid & 15) * 16;
            const float* p = xb + (size_t)(r0 + row) * D_ + cf;
            float f[16];
            #pragma unroll
            for (int i = 0; i < 4; i++) {
                float4 v = *(const float4*)(p + i * 4);
                f[4*i] = v.x; f[4*i+1] = v.y; f[4*i+2] = v.z; f[4*i+3] = v.w;
            }
            #pragma unroll
            for (int i = 0; i < 8; i++)
                Xi[row * 140 + (tid & 15) * 8 + i] = (h2){(_Float16)f[2*i], (_Float16)f[2*i+1]};
        }
        __syncthreads();

        float acc3[12][2] = {};
        for (int jc = 0; jc < 12; jc++) {
            if (jc) __syncthreads();
            {   // stage Xj: 32 rows x 256 cols; thread (row=tid>>3) covers 32 floats at (tid&7)*32
                const int row = tid >> 3, cf = (tid & 7) * 32;
                const float* p = xb + (size_t)(jc * 32 + row) * D_ + cf;
                #pragma unroll
                for (int g = 0; g < 2; g++) {
                    float f[16];
                    #pragma unroll
                    for (int i = 0; i < 4; i++) {
                        float4 v = *(const float4*)(p + g * 16 + i * 4);
                        f[4*i] = v.x; f[4*i+1] = v.y; f[4*i+2] = v.z; f[4*i+3] = v.w;
                    }
                    #pragma unroll
                    for (int i = 0; i < 8; i++)
                        Xj[row * 140 + (tid & 7) * 16 + g * 8 + i] =
                            (h2){(_Float16)f[2*i], (_Float16)f[2*i+1]};
                }
            }
            __syncthreads();
            #pragma unroll
            for (int kk = 0; kk < 32; kk++) {
                uint4 iv = *(const uint4*)&Xi[ty * 140 + kk * 4];
                uint4 wv = *(const uint4*)&Ws[kk * 4];
                h2 ai[4] = {__builtin_bit_cast(h2, iv.x), __builtin_bit_cast(h2, iv.y),
                            __builtin_bit_cast(h2, iv.z), __builtin_bit_cast(h2, iv.w)};
                h2 wp[4] = {__builtin_bit_cast(h2, wv.x), __builtin_bit_cast(h2, wv.y),
                            __builtin_bit_cast(h2, wv.z), __builtin_bit_cast(h2, wv.w)};
                #pragma unroll
                for (int jj = 0; jj < 2; jj++) {
                    uint4 jv = *(const uint4*)&Xj[(tx + 16 * jj) * 140 + kk * 4];
                    h2 bj[4] = {__builtin_bit_cast(h2, jv.x), __builtin_bit_cast(h2, jv.y),
                                __builtin_bit_cast(h2, jv.z), __builtin_bit_cast(h2, jv.w)};
                    float a = acc3[jc][jj];
                    #pragma unroll
                    for (int e = 0; e < 4; e++)
                        a = FDOT2(habs2(ai[e] - bj[e]), wp[e], a);
                    acc3[jc][jj] = a;
                }
            }
        }

        // mask + leaky + softmax (row reduction over the 16 lanes sharing ty)
        const int bn = load_boxnum(box_num, b);
        const int i_ = r0 + ty;
        const bool vi = i_ < bn;
        float m = -1e30f;
        #pragma unroll
        for (int jc = 0; jc < 12; jc++)
            #pragma unroll
            for (int jj = 0; jj < 2; jj++) {
                int j_ = jc * 32 + tx + 16 * jj;
                float v = acc3[jc][jj];
                if (!(vi && (j_ < bn))) v -= sumw;
                v = v > 0.f ? v : 0.01f * v;
                acc3[jc][jj] = v;
                m = fmaxf(m, v);
            }
        #pragma unroll
        for (int off = 8; off > 0; off >>= 1) m = fmaxf(m, __shfl_xor(m, off));
        const float* arow = adj + ((size_t)b * N_ + i_) * N_;
        float e[12][2], s = 0.f;
        #pragma unroll
        for (int jc = 0; jc < 12; jc++)
            #pragma unroll
            for (int jj = 0; jj < 2; jj++) {
                int j_ = jc * 32 + tx + 16 * jj;
                e[jc][jj] = arow[j_] * expf(acc3[jc][jj] - m);
                s += e[jc][jj];
            }
        #pragma unroll
        for (int off = 8; off > 0; off >>= 1) s += __shfl_xor(s, off);
        float inv = 1.0f / s;
        float* orow = soft_adj + ((size_t)b * N_ + i_) * N_;
        #pragma unroll
        for (int jc = 0; jc < 12; jc++)
            #pragma unroll
            for (int jj = 0; jj < 2; jj++)
                orow[jc * 32 + tx + 16 * jj] = e[jc][jj] * inv + 1e-10f;
    }
}

extern "C" void kernel_launch(void* const* d_in, const int* in_sizes, int n_in,
                              void* d_out, int out_size, void* d_ws, size_t ws_size,
                              hipStream_t stream) {
    const float* x       = (const float*)d_in[0];
    const float* adj     = (const float*)d_in[1];
    const int*   box_num = (const int*)d_in[2];
    const float* fc1_w   = (const float*)d_in[3];
    const float* fc1_b   = (const float*)d_in[4];
    const float* fc2_w   = (const float*)d_in[5];
    const float* fc2_b   = (const float*)d_in[6];
    const float* learn_w = (const float*)d_in[7];

    float* soft_adj = (float*)d_out;
    float* xhat     = (float*)d_out + (size_t)B_ * N_ * N_;

    unsigned* cnt = (unsigned*)d_ws;
    bh* wsb = (bh*)((char*)d_ws + 512);

    hipMemsetAsync(d_ws, 0, 512, stream);
    fused_kernel<<<GRID, 256, 0, stream>>>(x, adj, box_num, fc1_w, fc1_b,
                                           fc2_w, fc2_b, learn_w,
                                           soft_adj, xhat, wsb, cnt);
}

// Round 9
// 218.549 us; speedup vs baseline: 1.0446x; 1.0446x over previous
//
#include <hip/hip_runtime.h>
#include <math.h>

// Problem constants (fixed by reference)
#define B_ 8
#define N_ 384
#define D_ 256
#define H_ 1024

typedef __bf16 bh;
typedef __bf16 bh4    __attribute__((ext_vector_type(4)));
typedef __bf16 bf16x8 __attribute__((ext_vector_type(8)));
typedef float  f32x4  __attribute__((ext_vector_type(4)));
typedef _Float16 h2   __attribute__((ext_vector_type(2)));

#if __has_builtin(__builtin_amdgcn_fdot2)
#define FDOT2(a,b,c) __builtin_amdgcn_fdot2((a),(b),(c),false)
#else
#define FDOT2(a,b,c) ((c) + (float)(a).x*(float)(b).x + (float)(a).y*(float)(b).y)
#endif

// async global->LDS, 16B per lane; HW dest = wave-uniform base + lane*16B.
#define GLDS16(gp, lp) __builtin_amdgcn_global_load_lds( \
    (const __attribute__((address_space(1))) unsigned*)(gp), \
    (__attribute__((address_space(3))) unsigned*)(lp), 16, 0, 0)

__device__ inline h2 habs2(h2 x) {
    unsigned u = __builtin_bit_cast(unsigned, x) & 0x7fff7fffu;
    return __builtin_bit_cast(h2, u);
}
__device__ inline void split2(float v, bh& h, bh& l) {
    h = (bh)v; l = (bh)(v - (float)h);
}
// box_num logically int64; harness may hand int32. box_num >= 1 always, so
// int64-LE layout has all odd words zero -> runtime-detectable.
__device__ inline int load_boxnum(const int* __restrict__ p, int b) {
    bool is64 = ((p[1] | p[3] | p[5] | p[7]) == 0);
    return is64 ? p[2 * b] : p[b];
}

// ---------------- prep: split x / fc1_w / fc2_w into bf16 hi/lo planes ----------------
__global__ __launch_bounds__(256) void prep_split(
        const float* __restrict__ x, const float* __restrict__ w1, const float* __restrict__ w2,
        bh* __restrict__ xh, bh* __restrict__ xl,
        bh* __restrict__ w1h, bh* __restrict__ w1l,
        bh* __restrict__ w2h, bh* __restrict__ w2l) {
    const int blk = blockIdx.x;
    const float* src; bh *dh, *dl; int idx;
    if (blk < 768)       { src = x;  dh = xh;  dl = xl;  idx = blk * 256 + threadIdx.x; }
    else if (blk < 1024) { src = w1; dh = w1h; dl = w1l; idx = (blk - 768) * 256 + threadIdx.x; }
    else                 { src = w2; dh = w2h; dl = w2l; idx = (blk - 1024) * 256 + threadIdx.x; }
    float4 v = ((const float4*)src)[idx];
    float f[4] = {v.x, v.y, v.z, v.w};
    bh4 hv, lv;
    #pragma unroll
    for (int i = 0; i < 4; i++) { bh h, l; split2(f[i], h, l); hv[i] = h; lv[i] = l; }
    *(bh4*)&dh[4 * (size_t)idx] = hv;
    *(bh4*)&dl[4 * (size_t)idx] = lv;
}

// ---------------- fused MLP: one block = 16 rows, c1 lives in LDS ----------------
// LDS map (bytes): xs [2 planes][16 rows][264 bh]      @ 0      (16896)
//                  c1 [2 planes][16 rows][1032 bh]     @ 16896  (66048)
//                  wbuf [2 bufs][2 planes][256x32 bh]  @ 82944  (65536)   total 148480
// W chunk layout: 16 sub-chunks of (16 rows x 32 k), 16B k-blocks XOR-swizzled by ((row>>1)&3)
// (verified pattern from r5). xs/c1: padded row-major (stride%32 words == 4 -> 2-way banks, free).
__global__ __launch_bounds__(256) void mlp_fused(
        const bh* __restrict__ xh, const bh* __restrict__ xl,
        const bh* __restrict__ w1h, const bh* __restrict__ w1l,
        const bh* __restrict__ w2h, const bh* __restrict__ w2l,
        const float* __restrict__ b1, const float* __restrict__ b2,
        float* __restrict__ xhat) {
    __shared__ __align__(16) unsigned char smem[148480];
    bh* xs = (bh*)smem;                       // plane l at +4224 bh
    bh* c1 = (bh*)(smem + 16896);             // plane l at +16512 bh
    bh* wb = (bh*)(smem + 82944);             // buf b at +b*16384, plane l at +8192

    const int tid = threadIdx.x, lane = tid & 63, w = tid >> 6;
    const int m0 = blockIdx.x * 16;
    const int l15 = lane & 15, q = lane >> 4;
    const int swq = q ^ ((l15 >> 1) & 3);
    // W staging role: wave w -> plane (w>>1), rows (w&1)*128 + c*16, c=0..7
    const int lr = lane >> 2, kb = lane & 3;
    const int kbp = kb ^ ((lr >> 1) & 3);
    const bh* wsrc1 = (w >> 1) ? w1l : w1h;
    const bh* wsrc2 = (w >> 1) ? w2l : w2h;
    const int prow0 = (w & 1) * 128;
    bh* wdst_base = &wb[(w >> 1) * 8192 + prow0 * 32 + lane * 8];

    // ---- stage x tile (16x256, both planes) via VALU b128 copies ----
    {
        const int row = tid >> 4, seg = (tid & 15) * 16;
        const bh* sh = xh + (size_t)(m0 + row) * 256 + seg;
        const bh* sl = xl + (size_t)(m0 + row) * 256 + seg;
        *(uint4*)&xs[row * 264 + seg]            = *(const uint4*)sh;
        *(uint4*)&xs[row * 264 + seg + 8]        = *(const uint4*)(sh + 8);
        *(uint4*)&xs[4224 + row * 264 + seg]     = *(const uint4*)sl;
        *(uint4*)&xs[4224 + row * 264 + seg + 8] = *(const uint4*)(sl + 8);
    }

    // ---- gemm1: c1(16x1024) = relu(x @ W1^T + b1), 32 steps (4 nchunks x 8 k0) ----
    // prestage step 0 into buf 0
    #pragma unroll
    for (int c = 0; c < 8; c++) {
        int row = 0 * 256 + prow0 + c * 16 + lr;           // nc=0,k0=0
        GLDS16(wsrc1 + (size_t)row * 256 + 0 + kbp * 8, wdst_base + c * 512);
    }
    f32x4 acc[4] = {};
    for (int s = 0; s < 32; s++) {
        __syncthreads();                                   // drains step-s loads (+x writes at s=0)
        if (s + 1 < 32) {
            int nc1 = (s + 1) >> 3, k01 = ((s + 1) & 7) * 32;
            bh* dst = wdst_base + ((s + 1) & 1) * 16384;
            #pragma unroll
            for (int c = 0; c < 8; c++) {
                int row = nc1 * 256 + prow0 + c * 16 + lr;
                GLDS16(wsrc1 + (size_t)row * 256 + k01 + kbp * 8, dst + c * 512);
            }
        }
        const int k0b = s & 7;
        const bh* wcur = &wb[(s & 1) * 16384];
        bf16x8 fah = *(const bf16x8*)&xs[l15 * 264 + k0b * 32 + q * 8];
        bf16x8 fal = *(const bf16x8*)&xs[4224 + l15 * 264 + k0b * 32 + q * 8];
        #pragma unroll
        for (int nt = 0; nt < 4; nt++) {
            int sc = (w * 4 + nt) * 512 + l15 * 32 + swq * 8;
            bf16x8 fbh = *(const bf16x8*)&wcur[sc];
            bf16x8 fbl = *(const bf16x8*)&wcur[8192 + sc];
            acc[nt] = __builtin_amdgcn_mfma_f32_16x16x32_bf16(fah, fbh, acc[nt], 0, 0, 0);
            acc[nt] = __builtin_amdgcn_mfma_f32_16x16x32_bf16(fah, fbl, acc[nt], 0, 0, 0);
            acc[nt] = __builtin_amdgcn_mfma_f32_16x16x32_bf16(fal, fbh, acc[nt], 0, 0, 0);
        }
        if (k0b == 7) {                                    // epilogue for nchunk s>>3
            int nc = s >> 3;
            #pragma unroll
            for (int nt = 0; nt < 4; nt++) {
                int h = nc * 256 + w * 64 + nt * 16 + l15;
                float bb = b1[h];
                #pragma unroll
                for (int reg = 0; reg < 4; reg++) {
                    int m = q * 4 + reg;
                    float v = fmaxf(acc[nt][reg] + bb, 0.f);
                    bh hi, lo; split2(v, hi, lo);
                    c1[m * 1032 + h] = hi;
                    c1[16512 + m * 1032 + h] = lo;
                }
                acc[nt] = (f32x4){0.f, 0.f, 0.f, 0.f};
            }
        }
    }

    // ---- gemm2: xhat(16x256) = c1 @ W2^T + b2, 32 k-chunks ----
    __syncthreads();                                       // c1 writes visible; gemm1 W reads done
    #pragma unroll
    for (int c = 0; c < 8; c++) {
        int row = prow0 + c * 16 + lr;
        GLDS16(wsrc2 + (size_t)row * 1024 + 0 + kbp * 8, wdst_base + c * 512);
    }
    f32x4 acc2[4] = {};
    for (int kc = 0; kc < 32; kc++) {
        __syncthreads();
        if (kc + 1 < 32) {
            bh* dst = wdst_base + ((kc + 1) & 1) * 16384;
            #pragma unroll
            for (int c = 0; c < 8; c++) {
                int row = prow0 + c * 16 + lr;
                GLDS16(wsrc2 + (size_t)row * 1024 + (kc + 1) * 32 + kbp * 8, dst + c * 512);
            }
        }
        const bh* wcur = &wb[(kc & 1) * 16384];
        bf16x8 fah = *(const bf16x8*)&c1[l15 * 1032 + kc * 32 + q * 8];
        bf16x8 fal = *(const bf16x8*)&c1[16512 + l15 * 1032 + kc * 32 + q * 8];
        #pragma unroll
        for (int nt = 0; nt < 4; nt++) {
            int sc = (w * 4 + nt) * 512 + l15 * 32 + swq * 8;
            bf16x8 fbh = *(const bf16x8*)&wcur[sc];
            bf16x8 fbl = *(const bf16x8*)&wcur[8192 + sc];
            acc2[nt] = __builtin_amdgcn_mfma_f32_16x16x32_bf16(fah, fbh, acc2[nt], 0, 0, 0);
            acc2[nt] = __builtin_amdgcn_mfma_f32_16x16x32_bf16(fah, fbl, acc2[nt], 0, 0, 0);
            acc2[nt] = __builtin_amdgcn_mfma_f32_16x16x32_bf16(fal, fbh, acc2[nt], 0, 0, 0);
        }
    }
    #pragma unroll
    for (int nt = 0; nt < 4; nt++) {
        int col = w * 64 + nt * 16 + l15;
        float bb = b2[col];
        #pragma unroll
        for (int reg = 0; reg < 4; reg++) {
            int m = q * 4 + reg;
            xhat[(size_t)(m0 + m) * 256 + col] = acc2[nt][reg] + bb;
        }
    }
}

// ---------------- dist (weighted L1 + mask + leaky) + softmax, fused ----------------
// 192 blocks = 8 batches x 24 row-blocks of 16 rows; j in 12 chunks of 32, dbuf-staged.
// LDS: Xi 16x140 h2 (8960 B) | Xj[2] 32x140 h2 (35840 B) | Ws 128 h2 (512 B) = 45312 B.
__global__ __launch_bounds__(256) void dist_softmax(
        const float* __restrict__ xhat, const float* __restrict__ adj,
        const int* __restrict__ box_num, const float* __restrict__ learn_w,
        float* __restrict__ soft_adj) {
    __shared__ __align__(16) unsigned char smem[45312];
    h2* Xi = (h2*)smem;                       // [16][140]
    h2* Xj = (h2*)(smem + 8960);              // [2][32][140]
    h2* Ws = (h2*)(smem + 8960 + 35840);      // [128]
    const int bidx = blockIdx.x;
    const int b = bidx / 24, rb = bidx % 24;
    const int r0 = rb * 16;
    const int tid = threadIdx.x, lane = tid & 63;
    const int ty = tid >> 4, tx = tid & 15;

    float sumw = learn_w[lane] + learn_w[lane + 64] + learn_w[lane + 128] + learn_w[lane + 192];
    #pragma unroll
    for (int off = 32; off > 0; off >>= 1) sumw += __shfl_xor(sumw, off);

    const float* xb = xhat + (size_t)b * N_ * D_;
    if (tid < 64) {
        float4 wv = ((const float4*)learn_w)[tid];
        Ws[tid * 2]     = (h2){(_Float16)wv.x, (_Float16)wv.y};
        Ws[tid * 2 + 1] = (h2){(_Float16)wv.z, (_Float16)wv.w};
    }
    {   // stage Xi: 16 rows x 256 cols
        const int row = tid >> 4, cf = (tid & 15) * 16;
        const float* p = xb + (size_t)(r0 + row) * D_ + cf;
        float f[16];
        #pragma unroll
        for (int i = 0; i < 4; i++) {
            float4 v = *(const float4*)(p + i * 4);
            f[4*i] = v.x; f[4*i+1] = v.y; f[4*i+2] = v.z; f[4*i+3] = v.w;
        }
        #pragma unroll
        for (int i = 0; i < 8; i++)
            Xi[row * 140 + (tid & 15) * 8 + i] = (h2){(_Float16)f[2*i], (_Float16)f[2*i+1]};
    }
    const int jrow = tid >> 3, jcf = (tid & 7) * 32;
    {   // stage Xj chunk 0 into buf 0
        const float* p = xb + (size_t)(jrow) * D_ + jcf;
        #pragma unroll
        for (int g = 0; g < 2; g++) {
            float f[16];
            #pragma unroll
            for (int i = 0; i < 4; i++) {
                float4 v = *(const float4*)(p + g * 16 + i * 4);
                f[4*i] = v.x; f[4*i+1] = v.y; f[4*i+2] = v.z; f[4*i+3] = v.w;
            }
            #pragma unroll
            for (int i = 0; i < 8; i++)
                Xj[jrow * 140 + (tid & 7) * 16 + g * 8 + i] =
                    (h2){(_Float16)f[2*i], (_Float16)f[2*i+1]};
        }
    }
    __syncthreads();

    float acc3[12][2] = {};
    for (int jc = 0; jc < 12; jc++) {
        // prefetch chunk jc+1 to registers (loads fly during compute)
        float pf[32];
        const bool has = (jc + 1) < 12;
        if (has) {
            const float* p = xb + (size_t)((jc + 1) * 32 + jrow) * D_ + jcf;
            #pragma unroll
            for (int i = 0; i < 8; i++) {
                float4 v = *(const float4*)(p + i * 4);
                pf[4*i] = v.x; pf[4*i+1] = v.y; pf[4*i+2] = v.z; pf[4*i+3] = v.w;
            }
        }
        // compute chunk jc from buf jc&1
        const h2* Xc = Xj + (jc & 1) * (32 * 140);
        #pragma unroll
        for (int kk = 0; kk < 32; kk++) {
            uint4 iv = *(const uint4*)&Xi[ty * 140 + kk * 4];
            uint4 wv = *(const uint4*)&Ws[kk * 4];
            h2 ai[4] = {__builtin_bit_cast(h2, iv.x), __builtin_bit_cast(h2, iv.y),
                        __builtin_bit_cast(h2, iv.z), __builtin_bit_cast(h2, iv.w)};
            h2 wp[4] = {__builtin_bit_cast(h2, wv.x), __builtin_bit_cast(h2, wv.y),
                        __builtin_bit_cast(h2, wv.z), __builtin_bit_cast(h2, wv.w)};
            #pragma unroll
            for (int jj = 0; jj < 2; jj++) {
                uint4 jv = *(const uint4*)&Xc[(tx + 16 * jj) * 140 + kk * 4];
                h2 bj[4] = {__builtin_bit_cast(h2, jv.x), __builtin_bit_cast(h2, jv.y),
                            __builtin_bit_cast(h2, jv.z), __builtin_bit_cast(h2, jv.w)};
                float a = acc3[jc][jj];
                #pragma unroll
                for (int e = 0; e < 4; e++)
                    a = FDOT2(habs2(ai[e] - bj[e]), wp[e], a);
                acc3[jc][jj] = a;
            }
        }
        // write prefetched chunk into the other buffer
        if (has) {
            h2* Xn = Xj + ((jc + 1) & 1) * (32 * 140);
            #pragma unroll
            for (int g = 0; g < 2; g++)
                #pragma unroll
                for (int i = 0; i < 8; i++)
                    Xn[jrow * 140 + (tid & 7) * 16 + g * 8 + i] =
                        (h2){(_Float16)pf[g*16 + 2*i], (_Float16)pf[g*16 + 2*i + 1]};
        }
        __syncthreads();
    }

    // mask + leaky + softmax (row reduction over the 16 lanes sharing ty)
    const int bn = load_boxnum(box_num, b);
    const int i_ = r0 + ty;
    const bool vi = i_ < bn;
    float m = -1e30f;
    #pragma unroll
    for (int jc = 0; jc < 12; jc++)
        #pragma unroll
        for (int jj = 0; jj < 2; jj++) {
            int j_ = jc * 32 + tx + 16 * jj;
            float v = acc3[jc][jj];
            if (!(vi && (j_ < bn))) v -= sumw;
            v = v > 0.f ? v : 0.01f * v;
            acc3[jc][jj] = v;
            m = fmaxf(m, v);
        }
    #pragma unroll
    for (int off = 8; off > 0; off >>= 1) m = fmaxf(m, __shfl_xor(m, off));
    const float* arow = adj + ((size_t)b * N_ + i_) * N_;
    float e[12][2], s = 0.f;
    #pragma unroll
    for (int jc = 0; jc < 12; jc++)
        #pragma unroll
        for (int jj = 0; jj < 2; jj++) {
            int j_ = jc * 32 + tx + 16 * jj;
            e[jc][jj] = arow[j_] * expf(acc3[jc][jj] - m);
            s += e[jc][jj];
        }
    #pragma unroll
    for (int off = 8; off > 0; off >>= 1) s += __shfl_xor(s, off);
    float inv = 1.0f / s;
    float* orow = soft_adj + ((size_t)b * N_ + i_) * N_;
    #pragma unroll
    for (int jc = 0; jc < 12; jc++)
        #pragma unroll
        for (int jj = 0; jj < 2; jj++)
            orow[jc * 32 + tx + 16 * jj] = e[jc][jj] * inv + 1e-10f;
}

extern "C" void kernel_launch(void* const* d_in, const int* in_sizes, int n_in,
                              void* d_out, int out_size, void* d_ws, size_t ws_size,
                              hipStream_t stream) {
    const float* x       = (const float*)d_in[0];
    const float* adj     = (const float*)d_in[1];
    const int*   box_num = (const int*)d_in[2];
    const float* fc1_w   = (const float*)d_in[3];
    const float* fc1_b   = (const float*)d_in[4];
    const float* fc2_w   = (const float*)d_in[5];
    const float* fc2_b   = (const float*)d_in[6];
    const float* learn_w = (const float*)d_in[7];

    float* soft_adj = (float*)d_out;
    float* xhat     = (float*)d_out + (size_t)B_ * N_ * N_;

    // ws planes (bh units): xh, xl (786432 ea) | w1h, w1l (262144 ea) | w2h, w2l (262144 ea)
    bh* xh  = (bh*)d_ws;
    bh* xl  = xh  + 786432;
    bh* w1h = xl  + 786432;
    bh* w1l = w1h + 262144;
    bh* w2h = w1l + 262144;
    bh* w2l = w2h + 262144;

    prep_split<<<1280, 256, 0, stream>>>(x, fc1_w, fc2_w, xh, xl, w1h, w1l, w2h, w2l);

    mlp_fused<<<192, 256, 0, stream>>>(xh, xl, w1h, w1l, w2h, w2l, fc1_b, fc2_b, xhat);

    dist_softmax<<<192, 256, 0, stream>>>(xhat, adj, box_num, learn_w, soft_adj);
}